// Round 9
// baseline (221.162 us; speedup 1.0000x reference)
//
#include <hip/hip_runtime.h>
#include <hip/hip_bf16.h>
#include <cstdint>

// Problem constants
#define NN   4
#define LL   4096      // 64*64
#define DD   18
#define CVV  128
#define CIN  256
#define CUU  10
#define HH   129
#define COO  10

typedef unsigned short ushort_t;
typedef __attribute__((ext_vector_type(8))) short short8v;   // 8 bf16 (4 VGPRs)
typedef __attribute__((ext_vector_type(4))) float f32x4;

// workspace layout (float offsets)
#define P_OFF    ((size_t)0)          // p fp32 4194304 f (later: Opart splits 0-1 fp32 [2][4][4096][128])
#define U_OFF    ((size_t)4194304)    // u fp32 163840 f (later out_pre)
#define VP_OFF   ((size_t)4358144)    // val_pre fp32 2097152 f (later Lp[4][16384])
#define QT_OFF   ((size_t)6455296)    // qt bf16 [4][4096][32]
#define KT_OFF   ((size_t)6717440)    // kt bf16 tile-swizzled [4][64 tiles][4KB]
#define VT_OFF   ((size_t)6979584)    // vt bf16 tile-swizzled [4][64 tiles][16KB]
#define VSC_OFF  ((size_t)8028160)
#define VSH_OFF  ((size_t)8028288)
#define S2_OFF   ((size_t)8028416)
#define SH2_OFF  ((size_t)8028432)
#define PART_OFF ((size_t)8028448)    // bn partials (<=2048 f)
#define KMAX_OFF ((size_t)8030496)    // kmax int bits [4][32]
#define EXT_OFF  ((size_t)8030624)    // Opart splits 2-3 fp32 [2][4][4096][128] = 4194304 f
#define WS_NEED4 ((EXT_OFF + 4194304) * 4)   // bytes for 4-split (~48.9 MB; r8 confirmed available)

static __device__ __forceinline__ ushort_t f2bf(float x) {
    unsigned int u = __float_as_uint(x);
    unsigned int r = (u + 0x7fffu + ((u >> 16) & 1u)) >> 16;
    return (ushort_t)r;
}

// ---------------- avg pool 3x3 stride 2 with LDS row staging (+ optional kmax zeroing) ----------------
__global__ __launch_bounds__(256) void pool2_kernel(const float* __restrict__ src,
                                                    float* __restrict__ dst,
                                                    int* __restrict__ kz) {
    if (kz != nullptr && blockIdx.x == 0 && threadIdx.x < 128) kz[threadIdx.x] = 0;
    int b = blockIdx.x;
    int plane = b >> 4;
    int rg = b & 15;
    __shared__ float rows[9][132];
    const float* sp = src + (size_t)plane * (HH * HH) + (size_t)(rg * 8) * HH;
    #pragma unroll
    for (int j = 0; j < 9; ++j) {
        if (threadIdx.x < HH) rows[j][threadIdx.x] = sp[(size_t)j * HH + threadIdx.x];
    }
    __syncthreads();
    int row = threadIdx.x >> 6, ow = threadIdx.x & 63;
    const float* r0 = rows[2 * row];
    const float* r1 = rows[2 * row + 1];
    const float* r2 = rows[2 * row + 2];
    int x = 2 * ow;
    float sum = r0[x] + r0[x + 1] + r0[x + 2]
              + r1[x] + r1[x + 1] + r1[x + 2]
              + r2[x] + r2[x + 1] + r2[x + 2];
    dst[(size_t)plane * 4096 + (size_t)(rg * 4 + row) * 64 + ow] = sum * (1.0f / 9.0f);
}

// ---------------- query + key 1x1 convs, kt tile-swizzled, kmax via atomicMax ----------------
__global__ __launch_bounds__(256) void qk2_kernel(const float* __restrict__ p,
                                                  const float* __restrict__ u,
                                                  const float* __restrict__ Wq,
                                                  const float* __restrict__ Wk,
                                                  ushort_t* __restrict__ qt,
                                                  char* __restrict__ kt_c,
                                                  int* __restrict__ kmaxb) {
    int n = blockIdx.x >> 6;
    int mb = blockIdx.x & 63;
    int tid = threadIdx.x;
    int mloc = tid & 63;
    int cs = tid >> 6;
    int m = mb * 64 + mloc;
    int hi = m >> 6, wi = m & 63;

    __shared__ float kacc[4][64][21];

    float coord[8];
    coord[0] = wi * (2.0f / 64.0f) - 1.0f;
    coord[1] = hi * (2.0f / 64.0f) - 1.0f;
    coord[2] = (wi + 1) * (2.0f / 64.0f) - 1.0f;
    coord[3] = (hi + 1) * (2.0f / 64.0f) - 1.0f;
    coord[4] = 0.5f * (coord[0] + coord[2]);
    coord[5] = 0.5f * (coord[1] + coord[3]);
    coord[6] = 1.0f / 64.0f;
    coord[7] = 1.0f / 64.0f;

    // K partial over c in [cs*64, cs*64+64)
    {
        float acc[DD];
        #pragma unroll
        for (int o = 0; o < DD; ++o) acc[o] = 0.0f;
        const float* pc = p + ((size_t)(n * CIN + cs * 64)) * LL + m;
        for (int c0 = 0; c0 < 64; ++c0) {
            float pv = pc[(size_t)c0 * LL];
            const float* wr = Wk + (cs * 64 + c0);
            #pragma unroll
            for (int o = 0; o < DD; ++o) acc[o] = fmaf(pv, wr[o * 264], acc[o]);
        }
        if (cs == 3) {
            #pragma unroll
            for (int j = 0; j < 8; ++j) {
                float cv = coord[j];
                #pragma unroll
                for (int o = 0; o < DD; ++o) acc[o] = fmaf(cv, Wk[o * 264 + CIN + j], acc[o]);
            }
        }
        #pragma unroll
        for (int o = 0; o < DD; ++o) kacc[cs][mloc][o] = acc[o];
    }
    // Q full on wave 0
    if (cs == 0) {
        float acc[DD];
        #pragma unroll
        for (int o = 0; o < DD; ++o) acc[o] = 0.0f;
        for (int cq = 0; cq < CUU; ++cq) {
            float uv = u[((size_t)(n * CUU + cq)) * LL + m];
            #pragma unroll
            for (int o = 0; o < DD; ++o) acc[o] = fmaf(uv, Wq[o * DD + cq], acc[o]);
        }
        #pragma unroll
        for (int j = 0; j < 8; ++j) {
            float cv = coord[j];
            #pragma unroll
            for (int o = 0; o < DD; ++o) acc[o] = fmaf(cv, Wq[o * DD + CUU + j], acc[o]);
        }
        union { short8v v[4]; ushort_t s[32]; } pk;
        #pragma unroll
        for (int o = 0; o < 32; ++o) pk.s[o] = (o < DD) ? f2bf(acc[o]) : (ushort_t)0;
        short8v* qrow = (short8v*)(qt + ((size_t)(n * LL) + m) * 32);
        #pragma unroll
        for (int j = 0; j < 4; ++j) qrow[j] = pk.v[j];
    }
    __syncthreads();
    // reduce 4 partials, write kt tile-swizzled; collect per-o max|k|
    {
        int j = cs;
        union { short8v v; ushort_t s[8]; } pk;
        #pragma unroll
        for (int i = 0; i < 8; ++i) {
            int o = j * 8 + i;
            float v = 0.0f;
            if (o < DD)
                v = kacc[0][mloc][o] + kacc[1][mloc][o] + kacc[2][mloc][o] + kacc[3][mloc][o];
            pk.s[i] = (o < DD) ? f2bf(v) : (ushort_t)0;
        }
        int byte = ((mloc << 6) | (j << 4)) ^ (((mloc >> 1) & 7) << 4);
        *(short8v*)(kt_c + (size_t)n * 262144 + (size_t)mb * 4096 + byte) = pk.v;

        // wave-reduce max |k| per o in this chunk (wave == cs, lanes == mloc)
        int mb8[8];
        #pragma unroll
        for (int i = 0; i < 8; ++i) mb8[i] = (int)(pk.s[i] & 0x7fffu);
        #pragma unroll
        for (int off = 1; off < 64; off <<= 1) {
            #pragma unroll
            for (int i = 0; i < 8; ++i) {
                int ov = __shfl_xor(mb8[i], off);
                mb8[i] = max(mb8[i], ov);
            }
        }
        if (mloc == 0) {
            #pragma unroll
            for (int i = 0; i < 8; ++i)
                atomicMax(&kmaxb[n * 32 + cs * 8 + i], mb8[i] << 16);
        }
    }
}

// ---------------- val pre-BN GEMM: block 32ch x 128m, thread 4ch x 4m, Wv in LDS ----------------
__global__ __launch_bounds__(256, 2) void val_gemm2_kernel(const float* __restrict__ p,
                                                           const float* __restrict__ Wv,
                                                           float* __restrict__ val_pre) {
    int b = blockIdx.x;          // 512 blocks: n(4) x cb(4) x mb(32)
    int n  = b >> 7;
    int cb = (b >> 5) & 3;
    int mb = b & 31;
    int tid = threadIdx.x;
    int cg = tid >> 5;           // 8 groups x 4ch
    int mg = tid & 31;           // 32 groups x 4m
    int ch0 = cb * 32;
    int m0 = mb * 128;

    __shared__ float Wt[256][36];

    {
        int c4 = tid & 63;
        int chq = tid >> 6;
        #pragma unroll
        for (int j = 0; j < 8; ++j) {
            int ch = chq * 8 + j;
            float4 v = *(const float4*)&Wv[(size_t)(ch0 + ch) * CIN + c4 * 4];
            Wt[c4 * 4 + 0][ch] = v.x;
            Wt[c4 * 4 + 1][ch] = v.y;
            Wt[c4 * 4 + 2][ch] = v.z;
            Wt[c4 * 4 + 3][ch] = v.w;
        }
    }
    __syncthreads();

    const float* pb = p + (size_t)n * CIN * LL + m0 + mg * 4;
    f32x4 a0 = {0.f,0.f,0.f,0.f}, a1 = {0.f,0.f,0.f,0.f};
    f32x4 a2 = {0.f,0.f,0.f,0.f}, a3 = {0.f,0.f,0.f,0.f};

    #pragma unroll 4
    for (int c = 0; c < CIN; ++c) {
        f32x4 pv = *(const f32x4*)(pb + (size_t)c * LL);
        f32x4 wv = *(const f32x4*)&Wt[c][cg * 4];
        a0 += pv * wv.x;
        a1 += pv * wv.y;
        a2 += pv * wv.z;
        a3 += pv * wv.w;
    }

    size_t out = ((size_t)(n * CVV + ch0 + cg * 4)) * LL + m0 + mg * 4;
    *(f32x4*)&val_pre[out]           = a0;
    *(f32x4*)&val_pre[out + LL]      = a1;
    *(f32x4*)&val_pre[out + 2 * LL]  = a2;
    *(f32x4*)&val_pre[out + 3 * LL]  = a3;
}

// ---------------- BN stats, two-stage (vectorized) ----------------
__global__ __launch_bounds__(256) void bn_partial_kernel(const float* __restrict__ src,
                                                         float* __restrict__ part, int C) {
    int ch = blockIdx.x >> 3;
    int s = blockIdx.x & 7;
    int n = s >> 1;
    int m0 = (s & 1) * 2048 + threadIdx.x * 8;
    const float* b = src + ((size_t)(n * C + ch)) * LL + m0;
    float4 a = *(const float4*)b;
    float4 d = *(const float4*)(b + 4);
    float s1 = a.x + a.y + a.z + a.w + d.x + d.y + d.z + d.w;
    float s2 = a.x*a.x + a.y*a.y + a.z*a.z + a.w*a.w
             + d.x*d.x + d.y*d.y + d.z*d.z + d.w*d.w;

    __shared__ float rs[4], rs2[4];
    #pragma unroll
    for (int off = 32; off; off >>= 1) {
        s1 += __shfl_down(s1, off);
        s2 += __shfl_down(s2, off);
    }
    int wid = threadIdx.x >> 6;
    if ((threadIdx.x & 63) == 0) { rs[wid] = s1; rs2[wid] = s2; }
    __syncthreads();
    if (threadIdx.x == 0) {
        part[(size_t)blockIdx.x * 2]     = rs[0] + rs[1] + rs[2] + rs[3];
        part[(size_t)blockIdx.x * 2 + 1] = rs2[0] + rs2[1] + rs2[2] + rs2[3];
    }
}

__global__ __launch_bounds__(128) void bn_finalize_kernel(const float* __restrict__ part,
                                                          const float* __restrict__ g,
                                                          const float* __restrict__ bta,
                                                          float* __restrict__ scale,
                                                          float* __restrict__ shift, int C) {
    int ch = threadIdx.x;
    if (ch >= C) return;
    float s1 = 0.0f, s2 = 0.0f;
    #pragma unroll
    for (int s = 0; s < 8; ++s) {
        s1 += part[(size_t)(ch * 8 + s) * 2];
        s2 += part[(size_t)(ch * 8 + s) * 2 + 1];
    }
    float mean = s1 * (1.0f / (NN * LL));
    float var = s2 * (1.0f / (NN * LL)) - mean * mean;
    float inv = rsqrtf(var + 1e-5f);
    float sc = g[ch] * inv;
    scale[ch] = sc;
    shift[ch] = bta[ch] - mean * sc;
}

// ---------------- apply BN + relu -> bf16 V, tile-swizzled, 8 m per thread ----------------
__global__ __launch_bounds__(256) void bn_apply_kernel(const float* __restrict__ val_pre,
                                                       const float* __restrict__ scale,
                                                       const float* __restrict__ shift,
                                                       char* __restrict__ vt_c) {
    int t = blockIdx.x * 256 + threadIdx.x;   // over NN*CVV*512
    int mq = t & 511;
    int ch = (t >> 9) & 127;
    int n = t >> 16;
    int m0 = mq * 8;
    const float* b = val_pre + ((size_t)(n * CVV + ch)) * LL + m0;
    float4 a = *(const float4*)b;
    float4 d = *(const float4*)(b + 4);
    float sc = scale[ch], sh = shift[ch];
    union { short8v v; ushort_t s[8]; } pk;
    pk.s[0] = f2bf(fmaxf(fmaf(a.x, sc, sh), 0.0f));
    pk.s[1] = f2bf(fmaxf(fmaf(a.y, sc, sh), 0.0f));
    pk.s[2] = f2bf(fmaxf(fmaf(a.z, sc, sh), 0.0f));
    pk.s[3] = f2bf(fmaxf(fmaf(a.w, sc, sh), 0.0f));
    pk.s[4] = f2bf(fmaxf(fmaf(d.x, sc, sh), 0.0f));
    pk.s[5] = f2bf(fmaxf(fmaf(d.y, sc, sh), 0.0f));
    pk.s[6] = f2bf(fmaxf(fmaf(d.z, sc, sh), 0.0f));
    pk.s[7] = f2bf(fmaxf(fmaf(d.w, sc, sh), 0.0f));
    int tile = m0 >> 6, mloc = m0 & 63;
    size_t byte = (size_t)n * 1048576 + (size_t)tile * 16384
                + (size_t)(((ch << 7) | (mloc << 1)) ^ ((ch & 7) << 4));
    *(short8v*)(vt_c + byte) = pk.v;
}

// ---------------- barrier-free flash attention: K/V direct from L1/L2 (frag-aligned global) ----------------
struct PW { union { ushort_t p[16][72]; float ot[16][20]; }; };

__global__ __launch_bounds__(256, 3) void attn_flash6_kernel(const ushort_t* __restrict__ qt,
                                                             const char* __restrict__ kt_c,
                                                             const char* __restrict__ vt_c,
                                                             const int* __restrict__ kmaxb,
                                                             float* __restrict__ Op01,
                                                             float* __restrict__ Op23,
                                                             float* __restrict__ Lp,
                                                             int nsp_log2) {
    int orig = blockIdx.x;                       // 256 << nsp_log2 blocks
    int xcd = orig & 7;
    int idx = orig >> 3;
    int qb, n, sM;
    if (nsp_log2 == 1) {                         // 512 blocks: 8 (n,sM) combos, one per XCD
        qb = idx; n = xcd >> 1; sM = xcd & 1;
    } else {                                     // 1024 blocks: 16 combos, two per XCD
        qb = idx >> 1;
        int combo = xcd * 2 + (idx & 1);
        n = combo >> 2; sM = combo & 3;
    }
    int ntiles = 64 >> nsp_log2;
    int tk64 = sM * ntiles;

    int tid = threadIdx.x;
    int w = tid >> 6, lane = tid & 63, c = lane & 15, g = lane >> 4;
    int l0w = qb * 64 + w * 16;

    __shared__ PW pws[4];                        // wave-private P tile / O-transpose scratch only

    const char* ktb = kt_c + (size_t)n * 262144;
    const char* vtb = vt_c + (size_t)n * 1048576;

    short8v qf = *(const short8v*)(qt + (((size_t)n * LL + l0w + c) << 5) + g * 8);
    int vxor = (c & 7) << 4;

    // ---- analytic row-max bound: M_row = sum_o |q_o| * kmax_o (identical across splits) ----
    float bound = 0.0f;
    {
        const int* km = kmaxb + n * 32 + g * 8;
        #pragma unroll
        for (int i = 0; i < 8; ++i) {
            float kv = __int_as_float(km[i]);
            float aq = __uint_as_float(((unsigned int)((ushort_t)qf[i]) & 0x7fffu) << 16);
            bound = fmaf(aq, kv, bound);
        }
        bound += __shfl_xor(bound, 16);
        bound += __shfl_xor(bound, 32);   // lanes with same c now hold row-c bound
    }
    float M[4];
    #pragma unroll
    for (int r = 0; r < 4; ++r) M[r] = __shfl(bound, g * 4 + r);

    f32x4 O[8];
    #pragma unroll
    for (int i = 0; i < 8; ++i) O[i] = (f32x4){0.f, 0.f, 0.f, 0.f};
    float Lacc[4] = {0.f, 0.f, 0.f, 0.f};

    // precomputed K fragment byte offsets (per t)
    int kby[4];
    #pragma unroll
    for (int t = 0; t < 4; ++t) {
        int krow = t * 16 + c;
        kby[t] = ((krow << 6) | (g << 4)) ^ (((krow >> 1) & 7) << 4);
    }

    for (int mt = 0; mt < ntiles; ++mt) {
        int tile = tk64 + mt;
        const char* kb = ktb + (size_t)tile * 4096;
        // QK: K A/B-frags straight from global (L1/L2-resident, frag-aligned layout)
        f32x4 S[4];
        #pragma unroll
        for (int t = 0; t < 4; ++t) {
            short8v kf = *(const short8v*)(kb + kby[t]);
            S[t] = __builtin_amdgcn_mfma_f32_16x16x32_bf16(qf, kf, (f32x4){0.f, 0.f, 0.f, 0.f}, 0, 0, 0);
        }
        // exp + P tile (wave-private LDS round-trip only; no block barrier anywhere)
        #pragma unroll
        for (int t = 0; t < 4; ++t) {
            #pragma unroll
            for (int r = 0; r < 4; ++r) {
                float pv = __expf(S[t][r] - M[r]);
                Lacc[r] += pv;
                pws[w].p[g * 4 + r][t * 16 + c] = f2bf(pv);
            }
        }
        short8v pa0 = *(const short8v*)&pws[w].p[c][g * 8];
        short8v pa1 = *(const short8v*)&pws[w].p[c][32 + g * 8];
        // PV: V B-frags straight from global (16 KB tile stays hot in L1)
        const char* vb = vtb + (size_t)tile * 16384;
        __builtin_amdgcn_s_setprio(1);
        #pragma unroll
        for (int ct = 0; ct < 8; ++ct) {
            int row = ct * 16 + c;
            int vby0 = (row << 7) | ((g << 4) ^ vxor);
            int vby1 = (row << 7) | (((1 << 6) | (g << 4)) ^ vxor);
            short8v v0 = *(const short8v*)(vb + vby0);
            short8v v1 = *(const short8v*)(vb + vby1);
            O[ct] = __builtin_amdgcn_mfma_f32_16x16x32_bf16(pa0, v0, O[ct], 0, 0, 0);
            O[ct] = __builtin_amdgcn_mfma_f32_16x16x32_bf16(pa1, v1, O[ct], 0, 0, 0);
        }
        __builtin_amdgcn_s_setprio(0);
    }
    #pragma unroll
    for (int off = 1; off < 16; off <<= 1) {
        #pragma unroll
        for (int r = 0; r < 4; ++r) Lacc[r] += __shfl_xor(Lacc[r], off);
    }

    // ---- transpose O per 16-ch tile via wave-private LDS, coalesced fp32 write ----
    float* opb = (sM < 2) ? Op01 : Op23;
    size_t obase = ((size_t)((sM & 1) * NN + n) * LL + l0w);
    #pragma unroll
    for (int ct = 0; ct < 8; ++ct) {
        #pragma unroll
        for (int r = 0; r < 4; ++r) pws[w].ot[g * 4 + r][c] = O[ct][r];
        float4 v = *(float4*)&pws[w].ot[c][g * 4];
        *(float4*)&opb[(obase + c) * CVV + ct * 16 + g * 4] = v;
    }
    if (c == 0) {
        #pragma unroll
        for (int r = 0; r < 4; ++r) {
            int row = l0w + g * 4 + r;
            Lp[sM * (NN * LL) + n * LL + row] = Lacc[r];
        }
    }
}

// ---------------- merge m-splits (pure sum: bound-M identical across splits) + projection ----------------
__global__ __launch_bounds__(256) void proj_merge_sum_kernel(const float* __restrict__ Op01,
                                                             const float* __restrict__ Op23,
                                                             const float* __restrict__ Lp,
                                                             const float* __restrict__ Wp,
                                                             float* __restrict__ out_pre,
                                                             int ns) {
    int idx = blockIdx.x * 256 + threadIdx.x;   // over NN*LL
    int n = idx >> 12;
    int l = idx & 4095;
    int nl = n * LL + l;

    float den = 0.0f;
    #pragma unroll
    for (int s = 0; s < 4; ++s)
        if (s < ns) den += Lp[s * (NN * LL) + nl];
    float inv = 1.0f / den;

    const float4* ob[4];
    #pragma unroll
    for (int s = 0; s < 4; ++s) {
        const float* base = (s < 2) ? Op01 : Op23;
        ob[s] = (const float4*)(base + ((size_t)((s & 1) * NN + n) * LL + l) * CVV);
    }

    float acc[COO];
    #pragma unroll
    for (int o = 0; o < COO; ++o) acc[o] = 0.0f;
    for (int c4 = 0; c4 < CVV / 4; ++c4) {
        float4 v = make_float4(0.f, 0.f, 0.f, 0.f);
        #pragma unroll
        for (int s = 0; s < 4; ++s) {
            if (s < ns) {
                float4 a = ob[s][c4];
                v.x += a.x; v.y += a.y; v.z += a.z; v.w += a.w;
            }
        }
        v.x *= inv; v.y *= inv; v.z *= inv; v.w *= inv;
        #pragma unroll
        for (int o = 0; o < COO; ++o) {
            const float* wr = Wp + o * CVV + c4 * 4;
            acc[o] = fmaf(v.x, wr[0], acc[o]);
            acc[o] = fmaf(v.y, wr[1], acc[o]);
            acc[o] = fmaf(v.z, wr[2], acc[o]);
            acc[o] = fmaf(v.w, wr[3], acc[o]);
        }
    }
    #pragma unroll
    for (int o = 0; o < COO; ++o)
        out_pre[((size_t)(n * COO + o)) * LL + l] = acc[o];
}

// ---------------- BN + relu + bilinear resize (align_corners=True) ----------------
__global__ __launch_bounds__(256) void resize_kernel(const float* __restrict__ out_pre,
                                                     const float* __restrict__ scale,
                                                     const float* __restrict__ shift,
                                                     float* __restrict__ out,
                                                     int total) {
    int idx = blockIdx.x * 256 + threadIdx.x;
    if (idx >= total) return;
    int ow = idx % HH;
    int t = idx / HH;
    int oh = t % HH;
    int t2 = t / HH;
    int o = t2 % COO;
    int n = t2 / COO;

    const float r = 63.0f / 128.0f;
    float y = oh * r;
    float x = ow * r;
    int y0 = (int)y;
    int x0 = (int)x;
    float wy = y - y0;
    float wx = x - x0;
    int y1 = min(y0 + 1, 63);
    int x1 = min(x0 + 1, 63);

    const float* base = out_pre + ((size_t)(n * COO + o)) * LL;
    float sc = scale[o], sh = shift[o];
    float v00 = fmaxf(fmaf(base[y0 * 64 + x0], sc, sh), 0.0f);
    float v01 = fmaxf(fmaf(base[y0 * 64 + x1], sc, sh), 0.0f);
    float v10 = fmaxf(fmaf(base[y1 * 64 + x0], sc, sh), 0.0f);
    float v11 = fmaxf(fmaf(base[y1 * 64 + x1], sc, sh), 0.0f);
    float top = v00 * (1.0f - wx) + v01 * wx;
    float bot = v10 * (1.0f - wx) + v11 * wx;
    out[idx] = top * (1.0f - wy) + bot * wy;
}

extern "C" void kernel_launch(void* const* d_in, const int* in_sizes, int n_in,
                              void* d_out, int out_size, void* d_ws, size_t ws_size,
                              hipStream_t stream) {
    (void)in_sizes; (void)n_in; (void)out_size;
    const float* p_fea = (const float*)d_in[0];
    const float* hu    = (const float*)d_in[1];
    const float* Wq    = (const float*)d_in[2];
    const float* Wk    = (const float*)d_in[3];
    const float* Wv    = (const float*)d_in[4];
    const float* g_v   = (const float*)d_in[5];
    const float* b_v   = (const float*)d_in[6];
    const float* Wp    = (const float*)d_in[7];
    const float* g_p   = (const float*)d_in[8];
    const float* b_p   = (const float*)d_in[9];

    float* ws = (float*)d_ws;
    float*    p       = ws + P_OFF;
    float*    u       = ws + U_OFF;
    float*    val_pre = ws + VP_OFF;
    ushort_t* qtb     = (ushort_t*)(ws + QT_OFF);
    char*     ktb     = (char*)(ws + KT_OFF);
    char*     vtb     = (char*)(ws + VT_OFF);
    float*    Op01    = ws + P_OFF;               // alias: p dead after qk2/val_gemm
    float*    Op23    = ws + EXT_OFF;             // used when ws_size allows 4-split
    float*    out_pre = ws + U_OFF;               // alias: u dead after qk2
    float*    Lpart   = ws + VP_OFF;              // alias: val_pre dead after bn_apply
    float*    vscale  = ws + VSC_OFF;
    float*    vshift  = ws + VSH_OFF;
    float*    scale2  = ws + S2_OFF;
    float*    shift2  = ws + SH2_OFF;
    float*    part    = ws + PART_OFF;
    int*      kmaxb   = (int*)(ws + KMAX_OFF);

    int nsp_log2 = (ws_size >= (size_t)WS_NEED4) ? 2 : 1;
    int ns = 1 << nsp_log2;

    pool2_kernel<<<NN * CIN * 16, 256, 0, stream>>>(p_fea, p, kmaxb);
    pool2_kernel<<<NN * CUU * 16, 256, 0, stream>>>(hu, u, nullptr);
    qk2_kernel<<<256, 256, 0, stream>>>(p, u, Wq, Wk, qtb, ktb, kmaxb);
    val_gemm2_kernel<<<512, 256, 0, stream>>>(p, Wv, val_pre);
    bn_partial_kernel<<<CVV * 8, 256, 0, stream>>>(val_pre, part, CVV);
    bn_finalize_kernel<<<1, 128, 0, stream>>>(part, g_v, b_v, vscale, vshift, CVV);
    bn_apply_kernel<<<(NN * CVV * 512) / 256, 256, 0, stream>>>(val_pre, vscale, vshift, vtb);
    attn_flash6_kernel<<<256 << nsp_log2, 256, 0, stream>>>(qtb, ktb, vtb, kmaxb,
                                                            Op01, Op23, Lpart, nsp_log2);
    proj_merge_sum_kernel<<<(NN * LL) / 256, 256, 0, stream>>>(Op01, Op23, Lpart, Wp,
                                                               out_pre, ns);
    bn_partial_kernel<<<COO * 8, 256, 0, stream>>>(out_pre, part, COO);
    bn_finalize_kernel<<<1, 128, 0, stream>>>(part, g_p, b_p, scale2, shift2, COO);
    {
        int total = NN * COO * HH * HH;
        resize_kernel<<<(total + 255) / 256, 256, 0, stream>>>(out_pre, scale2, shift2,
                                                               (float*)d_out, total);
    }
}

// Round 10
// 153.015 us; speedup vs baseline: 1.4454x; 1.4454x over previous
//
#include <hip/hip_runtime.h>
#include <hip/hip_bf16.h>
#include <cstdint>

// Problem constants
#define NN   4
#define LL   4096      // 64*64
#define DD   18
#define CVV  128
#define CIN  256
#define CUU  10
#define HH   129
#define COO  10

typedef unsigned short ushort_t;
typedef __attribute__((ext_vector_type(8))) short short8v;   // 8 bf16 (4 VGPRs)
typedef __attribute__((ext_vector_type(4))) float f32x4;

// workspace layout (float offsets)
#define P_OFF    ((size_t)0)          // p fp32 4194304 f (dead after qk2/val_gemm)
#define U_OFF    ((size_t)4194304)    // u fp32 163840 f (later out_pre)
#define VP_OFF   ((size_t)4358144)    // val_pre fp32 2097152 f (later Lp[2][16384] + ypart[2][16384][10])
#define QT_OFF   ((size_t)6455296)    // qt bf16 [4][4096][32]
#define KT_OFF   ((size_t)6717440)    // kt bf16 tile-swizzled [4][64 tiles][4KB]
#define VT_OFF   ((size_t)6979584)    // vt bf16 tile-swizzled [4][64 tiles][16KB]
#define VSC_OFF  ((size_t)8028160)
#define VSH_OFF  ((size_t)8028288)
#define S2_OFF   ((size_t)8028416)
#define SH2_OFF  ((size_t)8028432)
#define PART_OFF ((size_t)8028448)    // bn partials (<=2048 f)
#define KMAX_OFF ((size_t)8030496)    // kmax int bits [4][32]
// Lp at VP_OFF (32768 f), ypart at VP_OFF+32768 (327680 f)

static __device__ __forceinline__ ushort_t f2bf(float x) {
    unsigned int u = __float_as_uint(x);
    unsigned int r = (u + 0x7fffu + ((u >> 16) & 1u)) >> 16;
    return (ushort_t)r;
}

static __device__ __forceinline__ void gload16(const void* g, void* l) {
    __builtin_amdgcn_global_load_lds(
        (const __attribute__((address_space(1))) void*)g,
        (__attribute__((address_space(3))) void*)l, 16, 0, 0);
}

// ---------------- avg pool 3x3 stride 2 with LDS row staging (+ optional kmax zeroing) ----------------
__global__ __launch_bounds__(256) void pool2_kernel(const float* __restrict__ src,
                                                    float* __restrict__ dst,
                                                    int* __restrict__ kz) {
    if (kz != nullptr && blockIdx.x == 0 && threadIdx.x < 128) kz[threadIdx.x] = 0;
    int b = blockIdx.x;
    int plane = b >> 4;
    int rg = b & 15;
    __shared__ float rows[9][132];
    const float* sp = src + (size_t)plane * (HH * HH) + (size_t)(rg * 8) * HH;
    #pragma unroll
    for (int j = 0; j < 9; ++j) {
        if (threadIdx.x < HH) rows[j][threadIdx.x] = sp[(size_t)j * HH + threadIdx.x];
    }
    __syncthreads();
    int row = threadIdx.x >> 6, ow = threadIdx.x & 63;
    const float* r0 = rows[2 * row];
    const float* r1 = rows[2 * row + 1];
    const float* r2 = rows[2 * row + 2];
    int x = 2 * ow;
    float sum = r0[x] + r0[x + 1] + r0[x + 2]
              + r1[x] + r1[x + 1] + r1[x + 2]
              + r2[x] + r2[x + 1] + r2[x + 2];
    dst[(size_t)plane * 4096 + (size_t)(rg * 4 + row) * 64 + ow] = sum * (1.0f / 9.0f);
}

// ---------------- query + key 1x1 convs, kt tile-swizzled, kmax via atomicMax ----------------
__global__ __launch_bounds__(256) void qk2_kernel(const float* __restrict__ p,
                                                  const float* __restrict__ u,
                                                  const float* __restrict__ Wq,
                                                  const float* __restrict__ Wk,
                                                  ushort_t* __restrict__ qt,
                                                  char* __restrict__ kt_c,
                                                  int* __restrict__ kmaxb) {
    int n = blockIdx.x >> 6;
    int mb = blockIdx.x & 63;
    int tid = threadIdx.x;
    int mloc = tid & 63;
    int cs = tid >> 6;
    int m = mb * 64 + mloc;
    int hi = m >> 6, wi = m & 63;

    __shared__ float kacc[4][64][21];

    float coord[8];
    coord[0] = wi * (2.0f / 64.0f) - 1.0f;
    coord[1] = hi * (2.0f / 64.0f) - 1.0f;
    coord[2] = (wi + 1) * (2.0f / 64.0f) - 1.0f;
    coord[3] = (hi + 1) * (2.0f / 64.0f) - 1.0f;
    coord[4] = 0.5f * (coord[0] + coord[2]);
    coord[5] = 0.5f * (coord[1] + coord[3]);
    coord[6] = 1.0f / 64.0f;
    coord[7] = 1.0f / 64.0f;

    // K partial over c in [cs*64, cs*64+64)
    {
        float acc[DD];
        #pragma unroll
        for (int o = 0; o < DD; ++o) acc[o] = 0.0f;
        const float* pc = p + ((size_t)(n * CIN + cs * 64)) * LL + m;
        for (int c0 = 0; c0 < 64; ++c0) {
            float pv = pc[(size_t)c0 * LL];
            const float* wr = Wk + (cs * 64 + c0);
            #pragma unroll
            for (int o = 0; o < DD; ++o) acc[o] = fmaf(pv, wr[o * 264], acc[o]);
        }
        if (cs == 3) {
            #pragma unroll
            for (int j = 0; j < 8; ++j) {
                float cv = coord[j];
                #pragma unroll
                for (int o = 0; o < DD; ++o) acc[o] = fmaf(cv, Wk[o * 264 + CIN + j], acc[o]);
            }
        }
        #pragma unroll
        for (int o = 0; o < DD; ++o) kacc[cs][mloc][o] = acc[o];
    }
    // Q full on wave 0
    if (cs == 0) {
        float acc[DD];
        #pragma unroll
        for (int o = 0; o < DD; ++o) acc[o] = 0.0f;
        for (int cq = 0; cq < CUU; ++cq) {
            float uv = u[((size_t)(n * CUU + cq)) * LL + m];
            #pragma unroll
            for (int o = 0; o < DD; ++o) acc[o] = fmaf(uv, Wq[o * DD + cq], acc[o]);
        }
        #pragma unroll
        for (int j = 0; j < 8; ++j) {
            float cv = coord[j];
            #pragma unroll
            for (int o = 0; o < DD; ++o) acc[o] = fmaf(cv, Wq[o * DD + CUU + j], acc[o]);
        }
        union { short8v v[4]; ushort_t s[32]; } pk;
        #pragma unroll
        for (int o = 0; o < 32; ++o) pk.s[o] = (o < DD) ? f2bf(acc[o]) : (ushort_t)0;
        short8v* qrow = (short8v*)(qt + ((size_t)(n * LL) + m) * 32);
        #pragma unroll
        for (int j = 0; j < 4; ++j) qrow[j] = pk.v[j];
    }
    __syncthreads();
    // reduce 4 partials, write kt tile-swizzled; collect per-o max|k|
    {
        int j = cs;
        union { short8v v; ushort_t s[8]; } pk;
        #pragma unroll
        for (int i = 0; i < 8; ++i) {
            int o = j * 8 + i;
            float v = 0.0f;
            if (o < DD)
                v = kacc[0][mloc][o] + kacc[1][mloc][o] + kacc[2][mloc][o] + kacc[3][mloc][o];
            pk.s[i] = (o < DD) ? f2bf(v) : (ushort_t)0;
        }
        int byte = ((mloc << 6) | (j << 4)) ^ (((mloc >> 1) & 7) << 4);
        *(short8v*)(kt_c + (size_t)n * 262144 + (size_t)mb * 4096 + byte) = pk.v;

        // wave-reduce max |k| per o in this chunk (wave == cs, lanes == mloc)
        int mb8[8];
        #pragma unroll
        for (int i = 0; i < 8; ++i) mb8[i] = (int)(pk.s[i] & 0x7fffu);
        #pragma unroll
        for (int off = 1; off < 64; off <<= 1) {
            #pragma unroll
            for (int i = 0; i < 8; ++i) {
                int ov = __shfl_xor(mb8[i], off);
                mb8[i] = max(mb8[i], ov);
            }
        }
        if (mloc == 0) {
            #pragma unroll
            for (int i = 0; i < 8; ++i)
                atomicMax(&kmaxb[n * 32 + cs * 8 + i], mb8[i] << 16);
        }
    }
}

// ---------------- val pre-BN GEMM: block 32ch x 128m, thread 4ch x 4m, Wv in LDS ----------------
__global__ __launch_bounds__(256, 2) void val_gemm2_kernel(const float* __restrict__ p,
                                                           const float* __restrict__ Wv,
                                                           float* __restrict__ val_pre) {
    int b = blockIdx.x;          // 512 blocks: n(4) x cb(4) x mb(32)
    int n  = b >> 7;
    int cb = (b >> 5) & 3;
    int mb = b & 31;
    int tid = threadIdx.x;
    int cg = tid >> 5;           // 8 groups x 4ch
    int mg = tid & 31;           // 32 groups x 4m
    int ch0 = cb * 32;
    int m0 = mb * 128;

    __shared__ float Wt[256][36];

    {
        int c4 = tid & 63;
        int chq = tid >> 6;
        #pragma unroll
        for (int j = 0; j < 8; ++j) {
            int ch = chq * 8 + j;
            float4 v = *(const float4*)&Wv[(size_t)(ch0 + ch) * CIN + c4 * 4];
            Wt[c4 * 4 + 0][ch] = v.x;
            Wt[c4 * 4 + 1][ch] = v.y;
            Wt[c4 * 4 + 2][ch] = v.z;
            Wt[c4 * 4 + 3][ch] = v.w;
        }
    }
    __syncthreads();

    const float* pb = p + (size_t)n * CIN * LL + m0 + mg * 4;
    f32x4 a0 = {0.f,0.f,0.f,0.f}, a1 = {0.f,0.f,0.f,0.f};
    f32x4 a2 = {0.f,0.f,0.f,0.f}, a3 = {0.f,0.f,0.f,0.f};

    #pragma unroll 4
    for (int c = 0; c < CIN; ++c) {
        f32x4 pv = *(const f32x4*)(pb + (size_t)c * LL);
        f32x4 wv = *(const f32x4*)&Wt[c][cg * 4];
        a0 += pv * wv.x;
        a1 += pv * wv.y;
        a2 += pv * wv.z;
        a3 += pv * wv.w;
    }

    size_t out = ((size_t)(n * CVV + ch0 + cg * 4)) * LL + m0 + mg * 4;
    *(f32x4*)&val_pre[out]           = a0;
    *(f32x4*)&val_pre[out + LL]      = a1;
    *(f32x4*)&val_pre[out + 2 * LL]  = a2;
    *(f32x4*)&val_pre[out + 3 * LL]  = a3;
}

// ---------------- BN stats, two-stage (vectorized) ----------------
__global__ __launch_bounds__(256) void bn_partial_kernel(const float* __restrict__ src,
                                                         float* __restrict__ part, int C) {
    int ch = blockIdx.x >> 3;
    int s = blockIdx.x & 7;
    int n = s >> 1;
    int m0 = (s & 1) * 2048 + threadIdx.x * 8;
    const float* b = src + ((size_t)(n * C + ch)) * LL + m0;
    float4 a = *(const float4*)b;
    float4 d = *(const float4*)(b + 4);
    float s1 = a.x + a.y + a.z + a.w + d.x + d.y + d.z + d.w;
    float s2 = a.x*a.x + a.y*a.y + a.z*a.z + a.w*a.w
             + d.x*d.x + d.y*d.y + d.z*d.z + d.w*d.w;

    __shared__ float rs[4], rs2[4];
    #pragma unroll
    for (int off = 32; off; off >>= 1) {
        s1 += __shfl_down(s1, off);
        s2 += __shfl_down(s2, off);
    }
    int wid = threadIdx.x >> 6;
    if ((threadIdx.x & 63) == 0) { rs[wid] = s1; rs2[wid] = s2; }
    __syncthreads();
    if (threadIdx.x == 0) {
        part[(size_t)blockIdx.x * 2]     = rs[0] + rs[1] + rs[2] + rs[3];
        part[(size_t)blockIdx.x * 2 + 1] = rs2[0] + rs2[1] + rs2[2] + rs2[3];
    }
}

__global__ __launch_bounds__(128) void bn_finalize_kernel(const float* __restrict__ part,
                                                          const float* __restrict__ g,
                                                          const float* __restrict__ bta,
                                                          float* __restrict__ scale,
                                                          float* __restrict__ shift, int C) {
    int ch = threadIdx.x;
    if (ch >= C) return;
    float s1 = 0.0f, s2 = 0.0f;
    #pragma unroll
    for (int s = 0; s < 8; ++s) {
        s1 += part[(size_t)(ch * 8 + s) * 2];
        s2 += part[(size_t)(ch * 8 + s) * 2 + 1];
    }
    float mean = s1 * (1.0f / (NN * LL));
    float var = s2 * (1.0f / (NN * LL)) - mean * mean;
    float inv = rsqrtf(var + 1e-5f);
    float sc = g[ch] * inv;
    scale[ch] = sc;
    shift[ch] = bta[ch] - mean * sc;
}

// ---------------- apply BN + relu -> bf16 V, tile-swizzled, 8 m per thread ----------------
__global__ __launch_bounds__(256) void bn_apply_kernel(const float* __restrict__ val_pre,
                                                       const float* __restrict__ scale,
                                                       const float* __restrict__ shift,
                                                       char* __restrict__ vt_c) {
    int t = blockIdx.x * 256 + threadIdx.x;   // over NN*CVV*512
    int mq = t & 511;
    int ch = (t >> 9) & 127;
    int n = t >> 16;
    int m0 = mq * 8;
    const float* b = val_pre + ((size_t)(n * CVV + ch)) * LL + m0;
    float4 a = *(const float4*)b;
    float4 d = *(const float4*)(b + 4);
    float sc = scale[ch], sh = shift[ch];
    union { short8v v; ushort_t s[8]; } pk;
    pk.s[0] = f2bf(fmaxf(fmaf(a.x, sc, sh), 0.0f));
    pk.s[1] = f2bf(fmaxf(fmaf(a.y, sc, sh), 0.0f));
    pk.s[2] = f2bf(fmaxf(fmaf(a.z, sc, sh), 0.0f));
    pk.s[3] = f2bf(fmaxf(fmaf(a.w, sc, sh), 0.0f));
    pk.s[4] = f2bf(fmaxf(fmaf(d.x, sc, sh), 0.0f));
    pk.s[5] = f2bf(fmaxf(fmaf(d.y, sc, sh), 0.0f));
    pk.s[6] = f2bf(fmaxf(fmaf(d.z, sc, sh), 0.0f));
    pk.s[7] = f2bf(fmaxf(fmaf(d.w, sc, sh), 0.0f));
    int tile = m0 >> 6, mloc = m0 & 63;
    size_t byte = (size_t)n * 1048576 + (size_t)tile * 16384
                + (size_t)(((ch << 7) | (mloc << 1)) ^ ((ch & 7) << 4));
    *(short8v*)(vt_c + byte) = pk.v;
}

// ---------------- flash attention + fused projection: LDS-staged K/V, 2-way m-split ----------------
struct PW { ushort_t p[16][72]; };

__global__ __launch_bounds__(256, 2) void attn_proj_kernel(const ushort_t* __restrict__ qt,
                                                           const char* __restrict__ kt_c,
                                                           const char* __restrict__ vt_c,
                                                           const int* __restrict__ kmaxb,
                                                           const float* __restrict__ Wp,
                                                           float* __restrict__ ypart,
                                                           float* __restrict__ Lp) {
    int orig = blockIdx.x;                       // 512
    int bid = ((orig & 7) << 6) | (orig >> 3);   // XCD-pinned: (n,sM) per XCD
    int qb = bid & 63;
    int sM = (bid >> 6) & 1;
    int n = bid >> 7;
    int tid = threadIdx.x;
    int w = tid >> 6, lane = tid & 63, c = lane & 15, g = lane >> 4;
    int l0w = qb * 64 + w * 16;

    __shared__ __align__(16) ushort_t K_t[2][2048];   // 2 x 4KB
    __shared__ __align__(16) ushort_t V_t[2][8192];   // 2 x 16KB
    __shared__ PW pws[4];
    __shared__ float Wpl[COO][CVV];                   // 5KB staged Wp

    for (int i = tid; i < COO * CVV; i += 256) Wpl[i >> 7][i & 127] = Wp[i];

    const char* ktb = kt_c + (size_t)n * 262144;
    const char* vtb = vt_c + (size_t)n * 1048576;
    int tk64 = sM * 32;

    short8v qf = *(const short8v*)(qt + (((size_t)n * LL + l0w + c) << 5) + g * 8);
    int vxor = (c & 7) << 4;

    // ---- analytic row-max bound: M_row = sum_o |q_o| * kmax_o (same for all splits) ----
    float bound = 0.0f;
    {
        const int* km = kmaxb + n * 32 + g * 8;
        #pragma unroll
        for (int i = 0; i < 8; ++i) {
            float kv = __int_as_float(km[i]);
            float aq = __uint_as_float(((unsigned int)((ushort_t)qf[i]) & 0x7fffu) << 16);
            bound = fmaf(aq, kv, bound);
        }
        bound += __shfl_xor(bound, 16);
        bound += __shfl_xor(bound, 32);   // lanes with same c now hold row-c bound
    }
    float M[4];
    #pragma unroll
    for (int r = 0; r < 4; ++r) M[r] = __shfl(bound, g * 4 + r);

    // ---- single pass: P = exp(S-M) (unnormalized), accumulate O, L ----
    f32x4 O[8];
    #pragma unroll
    for (int i = 0; i < 8; ++i) O[i] = (f32x4){0.f, 0.f, 0.f, 0.f};
    float Lacc[4] = {0.f, 0.f, 0.f, 0.f};

    {
        const char* ks = ktb + (size_t)tk64 * 4096 + w * 1024 + lane * 16;
        gload16(ks, (char*)K_t[0] + w * 1024);
        const char* vs = vtb + (size_t)tk64 * 16384 + w * 4096 + lane * 16;
        #pragma unroll
        for (int i = 0; i < 4; ++i)
            gload16(vs + i * 1024, (char*)V_t[0] + w * 4096 + i * 1024);
    }
    __syncthreads();
    int buf = 0;
    for (int mt = 0; mt < 32; ++mt) {
        if (mt + 1 < 32) {
            const char* ks = ktb + (size_t)(tk64 + mt + 1) * 4096 + w * 1024 + lane * 16;
            gload16(ks, (char*)K_t[buf ^ 1] + w * 1024);
            const char* vs = vtb + (size_t)(tk64 + mt + 1) * 16384 + w * 4096 + lane * 16;
            #pragma unroll
            for (int i = 0; i < 4; ++i)
                gload16(vs + i * 1024, (char*)V_t[buf ^ 1] + w * 4096 + i * 1024);
        }
        // QK
        f32x4 S[4];
        const char* kb = (const char*)K_t[buf];
        #pragma unroll
        for (int t = 0; t < 4; ++t) {
            int krow = t * 16 + c;
            int kby = ((krow << 6) | (g << 4)) ^ (((krow >> 1) & 7) << 4);
            short8v kf = *(const short8v*)(kb + kby);
            S[t] = __builtin_amdgcn_mfma_f32_16x16x32_bf16(qf, kf, (f32x4){0.f, 0.f, 0.f, 0.f}, 0, 0, 0);
        }
        // exp + P tile (wave-private)
        #pragma unroll
        for (int t = 0; t < 4; ++t) {
            #pragma unroll
            for (int r = 0; r < 4; ++r) {
                float pv = __expf(S[t][r] - M[r]);
                Lacc[r] += pv;
                pws[w].p[g * 4 + r][t * 16 + c] = f2bf(pv);
            }
        }
        short8v pa0 = *(const short8v*)&pws[w].p[c][g * 8];
        short8v pa1 = *(const short8v*)&pws[w].p[c][32 + g * 8];
        // PV
        const char* vb = (const char*)V_t[buf];
        __builtin_amdgcn_s_setprio(1);
        #pragma unroll
        for (int ct = 0; ct < 8; ++ct) {
            int row = ct * 16 + c;
            int vby0 = (row << 7) | ((g << 4) ^ vxor);
            int vby1 = (row << 7) | (((1 << 6) | (g << 4)) ^ vxor);
            short8v v0 = *(const short8v*)(vb + vby0);
            short8v v1 = *(const short8v*)(vb + vby1);
            O[ct] = __builtin_amdgcn_mfma_f32_16x16x32_bf16(pa0, v0, O[ct], 0, 0, 0);
            O[ct] = __builtin_amdgcn_mfma_f32_16x16x32_bf16(pa1, v1, O[ct], 0, 0, 0);
        }
        __builtin_amdgcn_s_setprio(0);
        __syncthreads();
        buf ^= 1;
    }
    #pragma unroll
    for (int off = 1; off < 16; off <<= 1) {
        #pragma unroll
        for (int r = 0; r < 4; ++r) Lacc[r] += __shfl_xor(Lacc[r], off);
    }

    // ---- fused projection: yp[o][r] = sum_ch O[q][ch] * Wp[o][ch] (per-lane partial over c-slice) ----
    float yp[COO][4];
    #pragma unroll
    for (int o = 0; o < COO; ++o)
        #pragma unroll
        for (int r = 0; r < 4; ++r) yp[o][r] = 0.0f;
    #pragma unroll
    for (int ct = 0; ct < 8; ++ct) {
        #pragma unroll
        for (int o = 0; o < COO; ++o) {
            float wv = Wpl[o][ct * 16 + c];
            #pragma unroll
            for (int r = 0; r < 4; ++r)
                yp[o][r] = fmaf(O[ct][r], wv, yp[o][r]);
        }
    }
    // reduce across the 16 c-lanes
    #pragma unroll
    for (int off = 1; off < 16; off <<= 1) {
        #pragma unroll
        for (int o = 0; o < COO; ++o)
            #pragma unroll
            for (int r = 0; r < 4; ++r)
                yp[o][r] += __shfl_xor(yp[o][r], off);
    }
    if (c == 0) {
        #pragma unroll
        for (int r = 0; r < 4; ++r) {
            size_t yrow = (size_t)(sM * (NN * LL) + n * LL + l0w + g * 4 + r);
            #pragma unroll
            for (int o = 0; o < COO; ++o)
                ypart[yrow * COO + o] = yp[o][r];
            Lp[yrow] = Lacc[r];
        }
    }
}

// ---------------- combine 2 m-splits: out_pre[n][o][l] = (y0+y1)/(L0+L1) ----------------
__global__ __launch_bounds__(256) void combine_kernel(const float* __restrict__ ypart,
                                                      const float* __restrict__ Lp,
                                                      float* __restrict__ out_pre) {
    int idx = blockIdx.x * 256 + threadIdx.x;   // over NN*LL
    int n = idx >> 12;
    int l = idx & 4095;
    int nl = n * LL + l;
    float inv = 1.0f / (Lp[nl] + Lp[NN * LL + nl]);
    const float* y0 = ypart + (size_t)nl * COO;
    const float* y1 = ypart + ((size_t)(NN * LL) + nl) * COO;
    #pragma unroll
    for (int o = 0; o < COO; ++o)
        out_pre[((size_t)(n * COO + o)) * LL + l] = (y0[o] + y1[o]) * inv;
}

// ---------------- BN + relu + bilinear resize (align_corners=True) ----------------
__global__ __launch_bounds__(256) void resize_kernel(const float* __restrict__ out_pre,
                                                     const float* __restrict__ scale,
                                                     const float* __restrict__ shift,
                                                     float* __restrict__ out,
                                                     int total) {
    int idx = blockIdx.x * 256 + threadIdx.x;
    if (idx >= total) return;
    int ow = idx % HH;
    int t = idx / HH;
    int oh = t % HH;
    int t2 = t / HH;
    int o = t2 % COO;
    int n = t2 / COO;

    const float r = 63.0f / 128.0f;
    float y = oh * r;
    float x = ow * r;
    int y0 = (int)y;
    int x0 = (int)x;
    float wy = y - y0;
    float wx = x - x0;
    int y1 = min(y0 + 1, 63);
    int x1 = min(x0 + 1, 63);

    const float* base = out_pre + ((size_t)(n * COO + o)) * LL;
    float sc = scale[o], sh = shift[o];
    float v00 = fmaxf(fmaf(base[y0 * 64 + x0], sc, sh), 0.0f);
    float v01 = fmaxf(fmaf(base[y0 * 64 + x1], sc, sh), 0.0f);
    float v10 = fmaxf(fmaf(base[y1 * 64 + x0], sc, sh), 0.0f);
    float v11 = fmaxf(fmaf(base[y1 * 64 + x1], sc, sh), 0.0f);
    float top = v00 * (1.0f - wx) + v01 * wx;
    float bot = v10 * (1.0f - wx) + v11 * wx;
    out[idx] = top * (1.0f - wy) + bot * wy;
}

extern "C" void kernel_launch(void* const* d_in, const int* in_sizes, int n_in,
                              void* d_out, int out_size, void* d_ws, size_t ws_size,
                              hipStream_t stream) {
    (void)in_sizes; (void)n_in; (void)out_size; (void)ws_size;
    const float* p_fea = (const float*)d_in[0];
    const float* hu    = (const float*)d_in[1];
    const float* Wq    = (const float*)d_in[2];
    const float* Wk    = (const float*)d_in[3];
    const float* Wv    = (const float*)d_in[4];
    const float* g_v   = (const float*)d_in[5];
    const float* b_v   = (const float*)d_in[6];
    const float* Wp    = (const float*)d_in[7];
    const float* g_p   = (const float*)d_in[8];
    const float* b_p   = (const float*)d_in[9];

    float* ws = (float*)d_ws;
    float*    p       = ws + P_OFF;
    float*    u       = ws + U_OFF;
    float*    val_pre = ws + VP_OFF;
    ushort_t* qtb     = (ushort_t*)(ws + QT_OFF);
    char*     ktb     = (char*)(ws + KT_OFF);
    char*     vtb     = (char*)(ws + VT_OFF);
    float*    out_pre = ws + U_OFF;               // alias: u dead after qk2
    float*    Lpart   = ws + VP_OFF;              // alias: val_pre dead after bn_apply
    float*    ypart   = ws + VP_OFF + 32768;      // [2][16384][10]
    float*    vscale  = ws + VSC_OFF;
    float*    vshift  = ws + VSH_OFF;
    float*    scale2  = ws + S2_OFF;
    float*    shift2  = ws + SH2_OFF;
    float*    part    = ws + PART_OFF;
    int*      kmaxb   = (int*)(ws + KMAX_OFF);

    pool2_kernel<<<NN * CIN * 16, 256, 0, stream>>>(p_fea, p, kmaxb);
    pool2_kernel<<<NN * CUU * 16, 256, 0, stream>>>(hu, u, nullptr);
    qk2_kernel<<<256, 256, 0, stream>>>(p, u, Wq, Wk, qtb, ktb, kmaxb);
    val_gemm2_kernel<<<512, 256, 0, stream>>>(p, Wv, val_pre);
    bn_partial_kernel<<<CVV * 8, 256, 0, stream>>>(val_pre, part, CVV);
    bn_finalize_kernel<<<1, 128, 0, stream>>>(part, g_v, b_v, vscale, vshift, CVV);
    bn_apply_kernel<<<(NN * CVV * 512) / 256, 256, 0, stream>>>(val_pre, vscale, vshift, vtb);
    attn_proj_kernel<<<512, 256, 0, stream>>>(qtb, ktb, vtb, kmaxb, Wp, ypart, Lpart);
    combine_kernel<<<(NN * LL) / 256, 256, 0, stream>>>(ypart, Lpart, out_pre);
    bn_partial_kernel<<<COO * 8, 256, 0, stream>>>(out_pre, part, COO);
    bn_finalize_kernel<<<1, 128, 0, stream>>>(part, g_p, b_p, scale2, shift2, COO);
    {
        int total = NN * COO * HH * HH;
        resize_kernel<<<(total + 255) / 256, 256, 0, stream>>>(out_pre, scale2, shift2,
                                                               (float*)d_out, total);
    }
}